// Round 6
// baseline (80.129 us; speedup 1.0000x reference)
//
#include <hip/hip_runtime.h>

namespace {
constexpr int N   = 64;
constexpr int D   = 32;
constexpr int PD  = 36;   // padded ind row (dwords): measured conflict-free (r1/r2)
constexpr int SHP = 68;   // sh row pad (r21-derived): write 2-way, phase2 read
                          // broadcast-within-group / 2-way across bsel = free (m136)
constexpr float LOG2E = 1.4426950408889634f;
constexpr float LN2   = 0.6931471805599453f;

typedef float f32x2 __attribute__((ext_vector_type(2)));

#if __has_builtin(__builtin_amdgcn_exp2f)
__device__ __forceinline__ float fexp2(float x) { return __builtin_amdgcn_exp2f(x); }
#else
__device__ __forceinline__ float fexp2(float x) { return exp2f(x); }
#endif
#if __has_builtin(__builtin_amdgcn_rcpf)
__device__ __forceinline__ float frcp(float x) { return __builtin_amdgcn_rcpf(x); }
#else
__device__ __forceinline__ float frcp(float x) { return 1.0f / x; }
#endif
__device__ __forceinline__ void wavebar() {
#if __has_builtin(__builtin_amdgcn_wave_barrier)
    __builtin_amdgcn_wave_barrier();
#endif
}

// r22: TWO b's PER BLOCK (r17 math verbatim). r20 probe: score math ~15us of
// ~31.5us fused, issue+trans-bound at its op-count floor; r21: phase-2 LDS
// has slack. Remaining lever = amortize everything b-independent:
//   grid 256, block 1024 (16 waves); wave owns rows 4w..4w+3 for BOTH b0,b1.
//   - staging + s-dots: once per 2 b's (was per b)
//   - gate: b-INDEPENDENT -> computed once per 2 b's (was duplicated)
//   - score: per (c,r) ONE shared s_load quad batch vq[4] + shared un/upl
//     chunk precompute feed BOTH b's bodies (only s0,s1 scalars differ);
//     s_load batches per row-instance HALVED; 2x independent acc chains
//     fill trans-pipe bubbles.
//   - softmax/phase2: per row-instance identical to r17 ([8] = (bsel,r)).
// LDS 64000 B (<64KB cap), 1 block/CU, 4 waves/SIMD (same occupancy as r17).
// Element math bit-identical to r17 -> absmax unchanged.
__global__ __launch_bounds__(1024, 4) void fused(
        const float* __restrict__ feature,
        const float* __restrict__ ind,
        float* __restrict__ out) {
    __shared__ float ind_lds[3][N][PD];   // 27648 B
    __shared__ float s_lds[3][2][N];      //  1536 B   [a][bsel][n]
    __shared__ float sh_lds[2][N][SHP];   // 34816 B   total 64000 B

    const int t    = threadIdx.x;
    const int lane = t & 63;
    const int wave = t >> 6;            // 0..15
    const int b0   = blockIdx.x << 1;

    // ---- stage indicator: 1536 float4, coalesced (once per 2 b's) ----
    {
        const float4* src = reinterpret_cast<const float4*>(ind);
#pragma unroll
        for (int idx = t; idx < 3 * N * D / 4; idx += 1024) {
            int a = idx >> 9;
            int r = idx & 511;
            int n = r >> 3;
            int k = r & 7;
            *reinterpret_cast<float4*>(&ind_lds[a][n][k * 4]) = src[idx];
        }
    }

    // ---- s[a][bsel][n] = feature[b,n,:] . ind[a,n,:] from GLOBAL, overlapped
    //      with staging (single barrier; r13-verified). 384 threads: a=t>>7,
    //      bsel=(t&127)>>6, n=t&63 (all pow2 decode). ----
    if (t < 384) {
        int a    = t >> 7;
        int rem  = t & 127;
        int bsel = rem >> 6;
        int n    = rem & 63;
        const float4* frow = reinterpret_cast<const float4*>(
            feature + ((size_t)(b0 + bsel) * N + n) * D);
        const float4* irow = reinterpret_cast<const float4*>(ind + (a * N + n) * D);
        f32x2 sa2 = {0.f, 0.f};
#pragma unroll
        for (int k = 0; k < 8; ++k) {
            float4 f4 = frow[k];
            float4 i4 = irow[k];
            sa2 = __builtin_elementwise_fma(f32x2{f4.x, f4.y}, f32x2{i4.x, i4.y}, sa2);
            sa2 = __builtin_elementwise_fma(f32x2{f4.z, f4.w}, f32x2{i4.z, i4.w}, sa2);
        }
        s_lds[a][bsel][n] = sa2.x + sa2.y;
    }
    __syncthreads();   // the ONLY block barrier

    // wave-uniform row indices (readfirstlane -> SGPR -> s_load addresses)
    int igu[4];
#pragma unroll
    for (int r = 0; r < 4; ++r)
        igu[r] = __builtin_amdgcn_readfirstlane(wave * 4 + r);

    // ---- gate bitmasks (b-INDEPENDENT, once per 2 b's): w-row ind1[lane] in
    //      VGPRs, a-rows via SCALAR loads from global ind0 ----
    unsigned long long gmask[4];
    {
        f32x2 wv[16];
#pragma unroll
        for (int k4 = 0; k4 < 8; ++k4) {
            float4 w4 = *reinterpret_cast<const float4*>(&ind_lds[1][lane][k4 * 4]);
            wv[k4 * 2 + 0] = f32x2{w4.x, w4.y};
            wv[k4 * 2 + 1] = f32x2{w4.z, w4.w};
        }
#pragma unroll
        for (int r = 0; r < 4; ++r) {
            f32x2 ga = {0.f, 0.f};
#pragma unroll
            for (int k4 = 0; k4 < 8; ++k4) {
                float4 a4 = *reinterpret_cast<const float4*>(ind + igu[r] * D + k4 * 4);  // s_load
                ga = __builtin_elementwise_fma(f32x2{a4.x, a4.y}, wv[k4 * 2 + 0], ga);
                ga = __builtin_elementwise_fma(f32x2{a4.z, a4.w}, wv[k4 * 2 + 1], ga);
            }
            gmask[r] = __ballot(ga.x + ga.y > 0.f);
        }
    }

    const float s1L0s = s_lds[1][0][lane] * LOG2E;
    const float s1L1s = s_lds[1][1][lane] * LOG2E;
    const f32x2 s1L0 = {s1L0s, s1L0s};
    const f32x2 s1L1 = {s1L1s, s1L1s};
    const f32x2 ln2v = {LN2, LN2};
    const f32x2 onev = {1.0f, 1.0f};
    const f32x2 zerv = {0.0f, 0.0f};

    // ---- hoisted row scalars (per b) ----
    float s0v0[4], s0v1[4];
#pragma unroll
    for (int r = 0; r < 4; ++r) {
        s0v0[r] = s_lds[0][0][wave * 4 + r] * LOG2E;
        s0v1[r] = s_lds[0][1][wave * 4 + r] * LOG2E;
    }

    // ---- score: sign-split packed loop (r17 math), both b's sharing vq[4]
    //      s_load batches and un/upl chunk precompute ----
    f32x2 sc0[4] = {{0.f, 0.f}, {0.f, 0.f}, {0.f, 0.f}, {0.f, 0.f}};
    f32x2 sc1[4] = {{0.f, 0.f}, {0.f, 0.f}, {0.f, 0.f}, {0.f, 0.f}};

#define SBODY(ACC, NEGA, FMAA, AM, FM, S1V)                                         \
    {                                                                               \
        const f32x2 amv = {(AM), (AM)};                                             \
        const f32x2 fmv = {(FM), (FM)};                                             \
        f32x2 acc = ACC;                                                            \
        _Pragma("unroll")                                                           \
        for (int k4 = 0; k4 < 4; ++k4) {                                            \
            const f32x2 vp0 = {vq[k4].x, vq[k4].y};                                 \
            const f32x2 vp1 = {vq[k4].z, vq[k4].w};                                 \
            _Pragma("unroll")                                                       \
            for (int h = 0; h < 2; ++h) {                                           \
                const f32x2 vp = h ? vp1 : vp0;                                     \
                f32x2 aneg = amv * NEGA[k4 * 2 + h];                                \
                f32x2 A    = __builtin_elementwise_fma(fmv, FMAA[k4 * 2 + h], onev);\
                f32x2 bL   = (S1V) * vp;                                            \
                f32x2 bneg = __builtin_elementwise_min(bL, zerv);                   \
                f32x2 B    = __builtin_elementwise_fma(                             \
                    __builtin_elementwise_max(bL, zerv), ln2v, onev);               \
                f32x2 mn   = aneg + bneg;                                           \
                f32x2 E    = {fexp2(mn.x), fexp2(mn.y)};                            \
                acc = __builtin_elementwise_fma(E * A, B, acc);                     \
            }                                                                       \
        }                                                                           \
        ACC = acc;                                                                  \
    }

#pragma unroll
    for (int c = 0; c < 2; ++c) {
        // per-chunk precompute: un = min(u,0), upl = max(u,0)*ln2 — SHARED by
        // both b's (b-independent; amortized over 8 row-instances)
        f32x2 un[8], upl[8];
#pragma unroll
        for (int k4 = 0; k4 < 4; ++k4) {
            float4 v = *reinterpret_cast<const float4*>(&ind_lds[0][lane][c * 16 + k4 * 4]);
            f32x2 x0 = {v.x, v.y}, x1 = {v.z, v.w};
            f32x2 n0 = __builtin_elementwise_min(x0, zerv);
            f32x2 n1 = __builtin_elementwise_min(x1, zerv);
            un[k4 * 2 + 0]  = n0;
            un[k4 * 2 + 1]  = n1;
            upl[k4 * 2 + 0] = (x0 - n0) * ln2v;
            upl[k4 * 2 + 1] = (x1 - n1) * ln2v;
        }
#pragma unroll
        for (int r = 0; r < 4; ++r) {
            // ONE shared s_load quad batch for this (c, row) — feeds both b's
            float4 vq[4];
#pragma unroll
            for (int k4 = 0; k4 < 4; ++k4)
                vq[k4] = *reinterpret_cast<const float4*>(
                    ind + N * D + igu[r] * D + c * 16 + k4 * 4);   // s_load

            // wave-uniform sign branches (s_cmp + s_cbranch), one per b
            const float s0ua = __uint_as_float(
                __builtin_amdgcn_readfirstlane(__float_as_uint(s0v0[r])));
            if (s0ua >= 0.f) {
                SBODY(sc0[r], un, upl, s0ua, s0ua, s1L0)
            } else {
                SBODY(sc0[r], upl, un, s0ua * LOG2E, s0ua * LN2, s1L0)
            }
            const float s0ub = __uint_as_float(
                __builtin_amdgcn_readfirstlane(__float_as_uint(s0v1[r])));
            if (s0ub >= 0.f) {
                SBODY(sc1[r], un, upl, s0ub, s0ub, s1L1)
            } else {
                SBODY(sc1[r], upl, un, s0ub * LOG2E, s0ub * LN2, s1L1)
            }
        }
    }
#undef SBODY

    // ---- 8-way-ILP wave softmax over j (64 lanes); q = bsel*4 + r ----
    float score[8];
#pragma unroll
    for (int r = 0; r < 4; ++r) {
        score[r]     = sc0[r].x + sc0[r].y;
        score[4 + r] = sc1[r].x + sc1[r].y;
    }
    float mx[8], e[8], sm[8];
#pragma unroll
    for (int q = 0; q < 8; ++q) mx[q] = score[q];
#pragma unroll
    for (int off = 32; off >= 1; off >>= 1) {
#pragma unroll
        for (int q = 0; q < 8; ++q) mx[q] = fmaxf(mx[q], __shfl_xor(mx[q], off));
    }
#pragma unroll
    for (int q = 0; q < 8; ++q) e[q] = fexp2((score[q] - mx[q]) * LOG2E);
#pragma unroll
    for (int q = 0; q < 8; ++q) sm[q] = e[q];
#pragma unroll
    for (int off = 32; off >= 1; off >>= 1) {
#pragma unroll
        for (int q = 0; q < 8; ++q) sm[q] += __shfl_xor(sm[q], off);
    }
#pragma unroll
    for (int q = 0; q < 8; ++q) {
        const int bsel = q >> 2;
        const int rr   = q & 3;
        const int row  = wave * 4 + rr;
        const float g  = (float)((gmask[rr] >> lane) & 1ull);   // gate b-indep
        sh_lds[bsel][row][lane] =
            (e[q] * g) * (s_lds[2][bsel][row] * frcp(sm[q]));
    }

    // NO block barrier: wave w wrote sh[bsel][4w..4w+3][*] and phase 2 below
    // reads only those rows (same-wave LDS RAW, lgkmcnt-ordered; r13/r17
    // pattern).
    wavebar();

    // ---- phase 2: out[b,i,:] = sh[b][i,:] @ ind2 ----
    // lane = (ri, dq): ri = lane>>3 -> (bsel = ri>>2, row = 4*wave + (ri&3)),
    // dq = lane&7. sh4 broadcast within 8-lane group / 2-way across bsel;
    // ind2 row uniform across wave -> 32-bank clean (r17-verified pattern).
    {
        const int ri   = lane >> 3;
        const int dq   = lane & 7;
        const int bsel = ri >> 2;
        const int row  = wave * 4 + (ri & 3);
        f32x2 acc0 = {0.f, 0.f}, acc1 = {0.f, 0.f};
#pragma unroll
        for (int j = 0; j < 64; j += 4) {
            float4 sh4 = *reinterpret_cast<const float4*>(&sh_lds[bsel][row][j]);
#pragma unroll
            for (int c = 0; c < 4; ++c) {
                float4 v4 = *reinterpret_cast<const float4*>(&ind_lds[2][j + c][dq * 4]);
                float  w  = (&sh4.x)[c];
                f32x2 wvv = {w, w};
                acc0 = __builtin_elementwise_fma(wvv, f32x2{v4.x, v4.y}, acc0);
                acc1 = __builtin_elementwise_fma(wvv, f32x2{v4.z, v4.w}, acc1);
            }
        }
        float4 acc = {acc0.x, acc0.y, acc1.x, acc1.y};
        *reinterpret_cast<float4*>(
            out + ((size_t)(b0 + bsel) * N + row) * D + dq * 4) = acc;
    }
}
}  // namespace

extern "C" void kernel_launch(void* const* d_in, const int* in_sizes, int n_in,
                              void* d_out, int out_size, void* d_ws, size_t ws_size,
                              hipStream_t stream) {
    const float* feature = (const float*)d_in[0];
    const float* ind     = (const float*)d_in[1];
    float*       out     = (float*)d_out;
    fused<<<256, 1024, 0, stream>>>(feature, ind, out);
}

// Round 7
// 78.373 us; speedup vs baseline: 1.0224x; 1.0224x over previous
//
#include <hip/hip_runtime.h>

namespace {
constexpr int N   = 64;
constexpr int D   = 32;
constexpr int PD  = 36;   // padded ind row (dwords): measured conflict-free (r1/r2)
constexpr int SHP = 72;   // sh row pad: 72%32==8 conflict-free residue (r11-r17)
constexpr float LOG2E = 1.4426950408889634f;
constexpr float LN2   = 0.6931471805599453f;

typedef float f32x2 __attribute__((ext_vector_type(2)));

#if __has_builtin(__builtin_amdgcn_exp2f)
__device__ __forceinline__ float fexp2(float x) { return __builtin_amdgcn_exp2f(x); }
#else
__device__ __forceinline__ float fexp2(float x) { return exp2f(x); }
#endif
#if __has_builtin(__builtin_amdgcn_rcpf)
__device__ __forceinline__ float frcp(float x) { return __builtin_amdgcn_rcpf(x); }
#else
__device__ __forceinline__ float frcp(float x) { return 1.0f / x; }
#endif
__device__ __forceinline__ void wavebar() {
#if __has_builtin(__builtin_amdgcn_wave_barrier)
    __builtin_amdgcn_wave_barrier();
#endif
}

// r23: FINAL MICRO PASS on r17 base (best @79.53). Cost map closed by r20-r22:
// dur = 40.6 fill (fixed) + 7.4 gap (fixed) + ~31.4 fused; fused = ~15 score
// (instruction floor) + ~16 distributed latency (insensitive to staging/gate/
// phase2/occupancy changes, 6 nulls). Two remaining bit-exact micro-levers:
//  1. B-side max elimination: max(bL,0) = bL - min(bL,0) -> per h-iter
//     7pk+4s -> 8pk+2s (-1 issue slot, ~7% of score inst content). Exact.
//  2. T5 s_setprio(1) around score: post-barrier waves drift (gate s_loads vs
//     score VALU/trans); priority favors score-resident waves (attn +4-7%,
//     m191; weaker regime here, expect 0-3%).
// Everything else r17 verbatim. Pre-commit: null result -> ROOFLINE declared.
__global__ __launch_bounds__(512, 4) void fused(
        const float* __restrict__ feature,
        const float* __restrict__ ind,
        float* __restrict__ out) {
    __shared__ float ind_lds[3][N][PD];   // 27648 B
    __shared__ float s_lds[3][N];         //   768 B
    __shared__ float sh_lds[N][SHP];      // 18432 B   total 46848 B -> 2 blocks/CU

    const int t    = threadIdx.x;
    const int lane = t & 63;
    const int wave = t >> 6;
    const int b    = blockIdx.x;

    // ---- stage indicator: 1536 float4, 3 per thread, coalesced ----
    {
        const float4* src = reinterpret_cast<const float4*>(ind);
#pragma unroll
        for (int idx = t; idx < 3 * N * D / 4; idx += 512) {
            int a = idx >> 9;
            int r = idx & 511;
            int n = r >> 3;
            int k = r & 7;
            *reinterpret_cast<float4*>(&ind_lds[a][n][k * 4]) = src[idx];
        }
    }

    // ---- s[a][n] = feature[b,n,:] . ind[a,n,:] from GLOBAL, overlapped with
    //      staging (single barrier; r13-verified) ----
    if (t < 3 * N) {
        int a = t >> 6, n = t & 63;
        const float4* frow = reinterpret_cast<const float4*>(feature + ((size_t)b * N + n) * D);
        const float4* irow = reinterpret_cast<const float4*>(ind + (a * N + n) * D);
        f32x2 sa2 = {0.f, 0.f};
#pragma unroll
        for (int k = 0; k < 8; ++k) {
            float4 f4 = frow[k];
            float4 i4 = irow[k];
            sa2 = __builtin_elementwise_fma(f32x2{f4.x, f4.y}, f32x2{i4.x, i4.y}, sa2);
            sa2 = __builtin_elementwise_fma(f32x2{f4.z, f4.w}, f32x2{i4.z, i4.w}, sa2);
        }
        s_lds[a][n] = sa2.x + sa2.y;
    }
    __syncthreads();   // the ONLY block barrier

    // wave-uniform row indices (readfirstlane -> SGPR -> s_load addresses)
    int igu[8];
#pragma unroll
    for (int r = 0; r < 8; ++r)
        igu[r] = __builtin_amdgcn_readfirstlane(wave * 8 + r);

    // ---- gate bitmasks: w-row (ind1[lane]) in VGPRs, a-rows via SCALAR loads
    //      from global ind0 (wave-uniform addr) -> s_load, SGPR operands ----
    unsigned long long gmask[8];
    {
        f32x2 wv[16];
#pragma unroll
        for (int k4 = 0; k4 < 8; ++k4) {
            float4 w4 = *reinterpret_cast<const float4*>(&ind_lds[1][lane][k4 * 4]);
            wv[k4 * 2 + 0] = f32x2{w4.x, w4.y};
            wv[k4 * 2 + 1] = f32x2{w4.z, w4.w};
        }
#pragma unroll
        for (int r = 0; r < 8; ++r) {
            f32x2 ga = {0.f, 0.f};
#pragma unroll
            for (int k4 = 0; k4 < 8; ++k4) {
                float4 a4 = *reinterpret_cast<const float4*>(ind + igu[r] * D + k4 * 4);  // s_load
                ga = __builtin_elementwise_fma(f32x2{a4.x, a4.y}, wv[k4 * 2 + 0], ga);
                ga = __builtin_elementwise_fma(f32x2{a4.z, a4.w}, wv[k4 * 2 + 1], ga);
            }
            gmask[r] = __ballot(ga.x + ga.y > 0.f);
        }
    }

    const float s1Ls = s_lds[1][lane] * LOG2E;
    const f32x2 s1L  = {s1Ls, s1Ls};
    const f32x2 ln2v = {LN2, LN2};
    const f32x2 onev = {1.0f, 1.0f};
    const f32x2 zerv = {0.0f, 0.0f};

    // ---- hoisted row scalars ----
    float s0v[8];
#pragma unroll
    for (int r = 0; r < 8; ++r) s0v[r] = s_lds[0][wave * 8 + r] * LOG2E;

    // ---- score: sign-split packed loop, 2 chunks of 16 d-elements (r14);
    //      v4 rows via SCALAR loads from global ind1 (wave-uniform addr).
    //      T5: raise wave priority for the whole score section. ----
#if __has_builtin(__builtin_amdgcn_s_setprio)
    __builtin_amdgcn_s_setprio(1);
#endif
    f32x2 sc2[8] = {{0.f, 0.f}, {0.f, 0.f}, {0.f, 0.f}, {0.f, 0.f},
                    {0.f, 0.f}, {0.f, 0.f}, {0.f, 0.f}, {0.f, 0.f}};

#define SCORE_BODY(NEGA, FMAA, AM, FM)                                              \
    {                                                                               \
        const f32x2 amv = {(AM), (AM)};                                             \
        const f32x2 fmv = {(FM), (FM)};                                             \
        f32x2 acc = sc2[r];                                                         \
        _Pragma("unroll")                                                           \
        for (int k4 = 0; k4 < 4; ++k4) {                                            \
            float4 v4 = *reinterpret_cast<const float4*>(                           \
                ind + N * D + igu[r] * D + c * 16 + k4 * 4);   /* s_load */         \
            f32x2 vp[2] = {f32x2{v4.x, v4.y}, f32x2{v4.z, v4.w}};                   \
            _Pragma("unroll")                                                       \
            for (int h = 0; h < 2; ++h) {                                           \
                f32x2 aneg = amv * NEGA[k4 * 2 + h];                                \
                f32x2 A    = __builtin_elementwise_fma(fmv, FMAA[k4 * 2 + h], onev);\
                f32x2 bL   = s1L * vp[h];                                           \
                f32x2 bneg = __builtin_elementwise_min(bL, zerv);                   \
                /* max(bL,0) = bL - bneg: bit-exact, kills the v_max pair */        \
                f32x2 B    = __builtin_elementwise_fma(bL - bneg, ln2v, onev);      \
                f32x2 mn   = aneg + bneg;                                           \
                f32x2 E    = {fexp2(mn.x), fexp2(mn.y)};                            \
                acc = __builtin_elementwise_fma(E * A, B, acc);                     \
            }                                                                       \
        }                                                                           \
        sc2[r] = acc;                                                               \
    }

#pragma unroll
    for (int c = 0; c < 2; ++c) {
        // per-chunk precompute: un = min(u,0), upl = max(u,0)*ln2  (16 f32x2 live)
        f32x2 un[8], upl[8];
#pragma unroll
        for (int k4 = 0; k4 < 4; ++k4) {
            float4 v = *reinterpret_cast<const float4*>(&ind_lds[0][lane][c * 16 + k4 * 4]);
            f32x2 x0 = {v.x, v.y}, x1 = {v.z, v.w};
            f32x2 n0 = __builtin_elementwise_min(x0, zerv);
            f32x2 n1 = __builtin_elementwise_min(x1, zerv);
            un[k4 * 2 + 0]  = n0;
            un[k4 * 2 + 1]  = n1;
            upl[k4 * 2 + 0] = (x0 - n0) * ln2v;
            upl[k4 * 2 + 1] = (x1 - n1) * ln2v;
        }
#pragma unroll
        for (int r = 0; r < 8; ++r) {
            // force wave-uniform scalar: s_cmp + s_cbranch, zero divergence
            const float s0u = __uint_as_float(
                __builtin_amdgcn_readfirstlane(__float_as_uint(s0v[r])));
            if (s0u >= 0.f) {
                SCORE_BODY(un, upl, s0u, s0u)
            } else {
                SCORE_BODY(upl, un, s0u * LOG2E, s0u * LN2)
            }
        }
    }
#undef SCORE_BODY
#if __has_builtin(__builtin_amdgcn_s_setprio)
    __builtin_amdgcn_s_setprio(0);
#endif

    float score[8];
#pragma unroll
    for (int r = 0; r < 8; ++r) score[r] = sc2[r].x + sc2[r].y;

    // ---- 8-way-ILP wave softmax over j (64 lanes) ----
    float mx[8], e[8], sm[8];
#pragma unroll
    for (int r = 0; r < 8; ++r) mx[r] = score[r];
#pragma unroll
    for (int off = 32; off >= 1; off >>= 1) {
#pragma unroll
        for (int r = 0; r < 8; ++r) mx[r] = fmaxf(mx[r], __shfl_xor(mx[r], off));
    }
#pragma unroll
    for (int r = 0; r < 8; ++r) e[r] = fexp2((score[r] - mx[r]) * LOG2E);
#pragma unroll
    for (int r = 0; r < 8; ++r) sm[r] = e[r];
#pragma unroll
    for (int off = 32; off >= 1; off >>= 1) {
#pragma unroll
        for (int r = 0; r < 8; ++r) sm[r] += __shfl_xor(sm[r], off);
    }
#pragma unroll
    for (int r = 0; r < 8; ++r) {
        const int ig  = wave * 8 + r;
        const float g = (float)((gmask[r] >> lane) & 1ull);
        sh_lds[ig][lane] = (e[r] * g) * (s_lds[2][ig] * frcp(sm[r]));
    }

    // NO block barrier: wave w wrote sh rows 8w..8w+7 and phase 2's thread t
    // (row t>>3) reads only those rows (same-wave LDS RAW, lgkmcnt-ordered;
    // r13/r14/r17-verified pattern).
    wavebar();

    // ---- phase 2: out[i,:] = sh[i,:] @ ind2; thread = (i_loc, d-quad) ----
    {
        const int i_loc = t >> 3;
        const int dq    = t & 7;
        f32x2 acc0 = {0.f, 0.f}, acc1 = {0.f, 0.f};
#pragma unroll
        for (int j = 0; j < 64; j += 4) {
            float4 sh4 = *reinterpret_cast<const float4*>(&sh_lds[i_loc][j]);
#pragma unroll
            for (int c = 0; c < 4; ++c) {
                float4 v4 = *reinterpret_cast<const float4*>(&ind_lds[2][j + c][dq * 4]);
                float  w  = (&sh4.x)[c];
                f32x2 wvv = {w, w};
                acc0 = __builtin_elementwise_fma(wvv, f32x2{v4.x, v4.y}, acc0);
                acc1 = __builtin_elementwise_fma(wvv, f32x2{v4.z, v4.w}, acc1);
            }
        }
        float4 acc = {acc0.x, acc0.y, acc1.x, acc1.y};
        *reinterpret_cast<float4*>(out + ((size_t)b * N + i_loc) * D + dq * 4) = acc;
    }
}
}  // namespace

extern "C" void kernel_launch(void* const* d_in, const int* in_sizes, int n_in,
                              void* d_out, int out_size, void* d_ws, size_t ws_size,
                              hipStream_t stream) {
    const float* feature = (const float*)d_in[0];
    const float* ind     = (const float*)d_in[1];
    float*       out     = (float*)d_out;
    fused<<<512, 512, 0, stream>>>(feature, ind, out);
}